// Round 5
// baseline (565.901 us; speedup 1.0000x reference)
//
#include <hip/hip_runtime.h>

#define BATCH 4
#define SEQ   4096
#define HID   4096
#define OUTF  4096
#define NA    8
#define RANK  64

typedef __attribute__((ext_vector_type(8))) short  short8;
typedef __attribute__((ext_vector_type(4))) float  f32x4;
typedef __attribute__((ext_vector_type(2))) unsigned int u32x2;

// round-half-up fp32 -> bf16 (inputs are finite Gaussians; no NaN handling needed)
__device__ __forceinline__ unsigned short cvt_bf16(float f) {
  return (unsigned short)((__float_as_uint(f) + 0x8000u) >> 16);
}
__device__ __forceinline__ unsigned int pack_bf16_2(float lo, float hi) {
  unsigned int a = __float_as_uint(lo);
  unsigned int b = __float_as_uint(hi);
  return ((a + 0x8000u) >> 16) | ((b + 0x8000u) & 0xFFFF0000u);
}

// ---------------------------------------------------------------------------
// Kernel 0: convert + transpose the small matrices so MFMA fragments are
// K-contiguous 16B loads.
//   Bct[a][r][h] = bf16(B[h][a][r])   (8 x 64 x 4096)
//   Act[a][o][r] = bf16(A[a][r][o])   (8 x 4096 x 64)
// ---------------------------------------------------------------------------
__global__ __launch_bounds__(256) void prep_kernel(
    const float* __restrict__ A, const float* __restrict__ Bm,
    unsigned short* __restrict__ Bct, unsigned short* __restrict__ Act) {
  __shared__ unsigned short lds[64 * 72];
  int bid = blockIdx.x;
  int t   = threadIdx.x;
  int lo  = t & 63;   // fast (coalesced) dim
  int hi4 = t >> 6;   // 0..3
  if (bid < 512) {
    int a  = bid >> 6;
    int h0 = (bid & 63) << 6;
    #pragma unroll
    for (int p = 0; p < 16; ++p) {          // read B[h][a][r], r = lo
      int hl = (p << 2) + hi4;
      float v = Bm[((size_t)(h0 + hl) * NA + a) * RANK + lo];
      lds[lo * 72 + hl] = cvt_bf16(v);      // lds[r][h]
    }
    __syncthreads();
    #pragma unroll
    for (int p = 0; p < 16; ++p) {          // write Bct[a][r][h], h = lo
      int rl = (p << 2) + hi4;
      Bct[((size_t)a * RANK + rl) * HID + h0 + lo] = lds[rl * 72 + lo];
    }
  } else {
    int b2 = bid - 512;
    int a  = b2 >> 6;
    int o0 = (b2 & 63) << 6;
    #pragma unroll
    for (int p = 0; p < 16; ++p) {          // read A[a][r][o], o = lo
      int rl = (p << 2) + hi4;
      float v = A[((size_t)a * RANK + rl) * OUTF + o0 + lo];
      lds[lo * 72 + rl] = cvt_bf16(v);      // lds[o][r]
    }
    __syncthreads();
    #pragma unroll
    for (int p = 0; p < 16; ++p) {          // write Act[a][o][r], r = lo
      int ol = (p << 2) + hi4;
      Act[((size_t)a * OUTF + o0 + ol) * RANK + lo] = lds[ol * 72 + lo];
    }
  }
}

// ---------------------------------------------------------------------------
// Fused kernel, v5: all global traffic is long contiguous per-wave bursts.
//   phase 1: per k-chunk of 1024, stage x[16][1024] (fp32->bf16) into LDS
//            with 1KB-contiguous wave loads, MFMA reads fragments from LDS
//            (XOR-swizzled, conflict-free). K split 8 ways across waves.
//   phase 2: per o-chunk of 512, MFMA results -> LDS out tile (swizzled),
//            then 512 threads stream it out as 1KB-contiguous wave stores
//            (plain stores; R4: nt stores inflate WRITE_SIZE 19%).
// R3/R4 established: not latency-bound, BW clamped ~2 TB/s by 16KB-strided
// 16-64B access granularity. This version trades tiny LDS traffic for
// full-burst DRAM access on both streams.
// LDS: xs(32.8KB) / red(33.3KB) / os(32.8KB) aliased in one buffer + bx ->
// 35.8 KB -> 4 blocks/CU x 8 waves = full occupancy cap.
// ---------------------------------------------------------------------------
__global__ __launch_bounds__(512, 8) void fused_kernel(
    const float* __restrict__ x, const int* __restrict__ ids,
    const unsigned short* __restrict__ Bct, const unsigned short* __restrict__ Act,
    float* __restrict__ out) {
  __shared__ float smem[8 * 16 * 65];          // 33.3 KB, aliased xs/red/os
  __shared__ unsigned short bx[16 * 72];       // Bx tile, bf16
  unsigned short* xs = (unsigned short*)smem;  // [16][1024] bf16, 16B-chunk swizzled
  float*          os = smem;                   // [16][512] f32, 16B-chunk swizzled
  float*          red = smem;                  // [8*16][65] f32 partials

  int bid   = blockIdx.x;
  int batch = bid & 3;          // XCD-pinned: XCD k -> batch k&3
  int s0    = (bid >> 2) << 4;
  int t     = threadIdx.x;
  int w     = t >> 6;           // 0..7
  int lane  = t & 63;
  int m     = lane & 15;
  int q     = lane >> 4;
  int a     = ids[batch];

  const float* xg = x + (size_t)(batch * SEQ + s0) * HID;
  const unsigned short* bbase = Bct + (size_t)a * RANK * HID;

  f32x4 acc[4];
  #pragma unroll
  for (int nt = 0; nt < 4; ++nt) acc[nt] = (f32x4){0.f, 0.f, 0.f, 0.f};

  // ---------------- phase 1: Bx = x_tile @ B_a ----------------
  for (int kc = 0; kc < 4; ++kc) {
    if (kc) __syncthreads();             // prev chunk's xs reads complete
    // stage: 8 rounds x 512 threads x f32x4 -> regs first (8-deep MLP),
    // each wave load = 64 lanes x 16B = 1KB contiguous.
    f32x4 v[8];
    #pragma unroll
    for (int r = 0; r < 8; ++r) {
      int flat = (r << 11) + (t << 2);
      int row  = flat >> 10;
      int col  = flat & 1023;
      v[r] = __builtin_nontemporal_load(
          (const f32x4*)(xg + (size_t)row * HID + (kc << 10) + col));
    }
    #pragma unroll
    for (int r = 0; r < 8; ++r) {
      int flat = (r << 11) + (t << 2);
      int row  = flat >> 10;
      int col  = flat & 1023;
      int csw  = (col >> 3) ^ (row & 7);     // swizzle 16B chunks by row
      u32x2 pk;
      pk[0] = pack_bf16_2(v[r][0], v[r][1]);
      pk[1] = pack_bf16_2(v[r][2], v[r][3]);
      *(u32x2*)&xs[row * 1024 + (csw << 3) + (col & 7)] = pk;
    }
    __syncthreads();
    // MFMA: wave w handles k_local in [w*128, w*128+128)
    #pragma unroll
    for (int j = 0; j < 4; ++j) {
      int kl  = (w << 7) + (j << 5) + (q << 3);
      int csw = (kl >> 3) ^ (m & 7);
      short8 af = *(const short8*)&xs[m * 1024 + (csw << 3)];
      int kglob = (kc << 10) + kl;
      #pragma unroll
      for (int nt = 0; nt < 4; ++nt) {
        short8 bf = *(const short8*)(bbase + (size_t)(nt * 16 + m) * HID + kglob);
        acc[nt] = __builtin_amdgcn_mfma_f32_16x16x32_bf16(af, bf, acc[nt], 0, 0, 0);
      }
    }
  }
  __syncthreads();   // all xs reads done before red overwrites the buffer

  // cross-wave reduce: C/D layout col = lane&15 (-> r), row = q*4+reg (-> s)
  #pragma unroll
  for (int nt = 0; nt < 4; ++nt)
    #pragma unroll
    for (int r = 0; r < 4; ++r)
      red[(w * 16 + q * 4 + r) * 65 + nt * 16 + m] = acc[nt][r];
  __syncthreads();

  if (t < 256) {
    int row = t >> 4;          // 0..15
    int rb  = (t & 15) << 2;   // 0,4,...,60
    float v0 = 0.f, v1 = 0.f, v2 = 0.f, v3 = 0.f;
    #pragma unroll
    for (int ww = 0; ww < 8; ++ww) {
      const float* rr = &red[(ww * 16 + row) * 65 + rb];
      v0 += rr[0]; v1 += rr[1]; v2 += rr[2]; v3 += rr[3];
    }
    const float sc = 1.0f / 64.0f;   // exact *1/64, commutes with bf16 rounding
    uint2 pk;
    pk.x = pack_bf16_2(v0 * sc, v1 * sc);
    pk.y = pack_bf16_2(v2 * sc, v3 * sc);
    *(uint2*)&bx[row * 72 + rb] = pk;
  }
  __syncthreads();   // bx ready; red fully consumed -> os may overwrite

  // ---------------- phase 2: out_tile = Bx @ A_a ----------------
  // Operand-swapped MFMA (A-frag = Act rows, B-frag = Bx): lane holds 4
  // contiguous o values -> stage to os (swizzled) -> streamed stores.
  short8 p0 = *(const short8*)&bx[m * 72 + (q << 3)];
  short8 p1 = *(const short8*)&bx[m * 72 + 32 + (q << 3)];
  const unsigned short* abase = Act + (size_t)a * OUTF * RANK;

  for (int oc = 0; oc < 8; ++oc) {
    int o0 = oc << 9;                       // this chunk: o in [o0, o0+512)
    #pragma unroll
    for (int nt = 0; nt < 4; ++nt) {
      const unsigned short* arow =
          abase + (size_t)(o0 + (w << 6) + nt * 16 + m) * RANK;
      short8 b0 = *(const short8*)(arow + (q << 3));
      short8 b1 = *(const short8*)(arow + 32 + (q << 3));
      f32x4 cc = (f32x4){0.f, 0.f, 0.f, 0.f};
      cc = __builtin_amdgcn_mfma_f32_16x16x32_bf16(b0, p0, cc, 0, 0, 0);
      cc = __builtin_amdgcn_mfma_f32_16x16x32_bf16(b1, p1, cc, 0, 0, 0);
      int ci  = (w << 4) + (nt << 2) + q;    // 16B chunk index within row
      *(f32x4*)&os[m * 512 + ((ci ^ (m & 7)) << 2)] = cc;
    }
    __syncthreads();
    // stream the 16x512 f32 tile: 4 rounds, 1KB contiguous per wave
    #pragma unroll
    for (int r = 0; r < 4; ++r) {
      int flat = (r << 11) + (t << 2);
      int row  = flat >> 9;
      int col  = flat & 511;
      int csw  = (col >> 2) ^ (row & 7);
      f32x4 vv = *(const f32x4*)&os[row * 512 + (csw << 2)];
      *(f32x4*)(out + (size_t)(batch * SEQ + s0 + row) * OUTF + o0 + col) = vv;
    }
    __syncthreads();   // os consumed before next chunk overwrites
  }
}

// ---------------------------------------------------------------------------
extern "C" void kernel_launch(void* const* d_in, const int* in_sizes, int n_in,
                              void* d_out, int out_size, void* d_ws, size_t ws_size,
                              hipStream_t stream) {
  const float* x   = (const float*)d_in[0];
  const int*   ids = (const int*)d_in[1];
  const float* A   = (const float*)d_in[2];
  const float* Bm  = (const float*)d_in[3];
  float*       out = (float*)d_out;

  // workspace layout (8 MB total):
  unsigned short* Bct = (unsigned short*)d_ws;                 // 8*64*4096*2 = 4 MB
  unsigned short* Act = Bct + (size_t)NA * RANK * HID;         // 8*4096*64*2 = 4 MB

  prep_kernel <<<1024, 256, 0, stream>>>(A, Bm, Bct, Act);
  fused_kernel<<<1024, 512, 0, stream>>>(x, ids, Bct, Act, out);
}

// Round 6
// 533.722 us; speedup vs baseline: 1.0603x; 1.0603x over previous
//
#include <hip/hip_runtime.h>

#define BATCH 4
#define SEQ   4096
#define HID   4096
#define OUTF  4096
#define NA    8
#define RANK  64

typedef __attribute__((ext_vector_type(8))) short  short8;
typedef __attribute__((ext_vector_type(4))) float  f32x4;
typedef __attribute__((ext_vector_type(2))) unsigned int u32x2;

// round-half-up fp32 -> bf16 (inputs are finite Gaussians; no NaN handling needed)
__device__ __forceinline__ unsigned short cvt_bf16(float f) {
  return (unsigned short)((__float_as_uint(f) + 0x8000u) >> 16);
}
__device__ __forceinline__ unsigned int pack_bf16_2(float lo, float hi) {
  unsigned int a = __float_as_uint(lo);
  unsigned int b = __float_as_uint(hi);
  return ((a + 0x8000u) >> 16) | ((b + 0x8000u) & 0xFFFF0000u);
}

// ---------------------------------------------------------------------------
// Kernel 0: convert + transpose the small matrices so MFMA fragments are
// K-contiguous 16B loads.
//   Bct[a][r][h] = bf16(B[h][a][r])   (8 x 64 x 4096)
//   Act[a][o][r] = bf16(A[a][r][o])   (8 x 4096 x 64)
// ---------------------------------------------------------------------------
__global__ __launch_bounds__(256) void prep_kernel(
    const float* __restrict__ A, const float* __restrict__ Bm,
    unsigned short* __restrict__ Bct, unsigned short* __restrict__ Act) {
  __shared__ unsigned short lds[64 * 72];
  int bid = blockIdx.x;
  int t   = threadIdx.x;
  int lo  = t & 63;   // fast (coalesced) dim
  int hi4 = t >> 6;   // 0..3
  if (bid < 512) {
    int a  = bid >> 6;
    int h0 = (bid & 63) << 6;
    #pragma unroll
    for (int p = 0; p < 16; ++p) {          // read B[h][a][r], r = lo
      int hl = (p << 2) + hi4;
      float v = Bm[((size_t)(h0 + hl) * NA + a) * RANK + lo];
      lds[lo * 72 + hl] = cvt_bf16(v);      // lds[r][h]
    }
    __syncthreads();
    #pragma unroll
    for (int p = 0; p < 16; ++p) {          // write Bct[a][r][h], h = lo
      int rl = (p << 2) + hi4;
      Bct[((size_t)a * RANK + rl) * HID + h0 + lo] = lds[rl * 72 + lo];
    }
  } else {
    int b2 = bid - 512;
    int a  = b2 >> 6;
    int o0 = (b2 & 63) << 6;
    #pragma unroll
    for (int p = 0; p < 16; ++p) {          // read A[a][r][o], o = lo
      int rl = (p << 2) + hi4;
      float v = A[((size_t)a * RANK + rl) * OUTF + o0 + lo];
      lds[lo * 72 + rl] = cvt_bf16(v);      // lds[o][r]
    }
    __syncthreads();
    #pragma unroll
    for (int p = 0; p < 16; ++p) {          // write Act[a][o][r], r = lo
      int ol = (p << 2) + hi4;
      Act[((size_t)a * OUTF + o0 + ol) * RANK + lo] = lds[ol * 72 + lo];
    }
  }
}

// ---------------------------------------------------------------------------
// Fused kernel, v6: burst global access (R5 mechanism, BW 2.0->2.5 TB/s)
// WITHOUT the register spill. R5's f32x4 v[8] staging (32 VGPR) overflowed
// the 64-VGPR cap from __launch_bounds__(512,8) -> scratch spill -> +95 MB
// WRITE / +72 MB FETCH. v6 stages in two batches of 4 (16 VGPR live).
//   phase 1: per k-chunk of 1024, stage x[16][1024] (fp32->bf16) into LDS
//            with 1KB-contiguous wave loads, MFMA reads fragments from LDS
//            (XOR-swizzled, conflict-free). K split 8 ways across waves.
//   phase 2: per o-chunk of 512, MFMA results -> LDS out tile (swizzled),
//            then 512 threads stream it out as 1KB-contiguous wave stores
//            (plain stores; R4: nt stores inflate WRITE_SIZE 19%).
// LDS: xs(32.8KB) / red(33.3KB) / os(32.8KB) aliased + bx -> 35.8 KB.
// ---------------------------------------------------------------------------
__global__ __launch_bounds__(512, 8) void fused_kernel(
    const float* __restrict__ x, const int* __restrict__ ids,
    const unsigned short* __restrict__ Bct, const unsigned short* __restrict__ Act,
    float* __restrict__ out) {
  __shared__ float smem[8 * 16 * 65];          // 33.3 KB, aliased xs/red/os
  __shared__ unsigned short bx[16 * 72];       // Bx tile, bf16
  unsigned short* xs = (unsigned short*)smem;  // [16][1024] bf16, 16B-chunk swizzled
  float*          os = smem;                   // [16][512] f32, 16B-chunk swizzled
  float*          red = smem;                  // [8*16][65] f32 partials

  int bid   = blockIdx.x;
  int batch = bid & 3;          // XCD-pinned: XCD k -> batch k&3
  int s0    = (bid >> 2) << 4;
  int t     = threadIdx.x;
  int w     = t >> 6;           // 0..7
  int lane  = t & 63;
  int m     = lane & 15;
  int q     = lane >> 4;
  int a     = ids[batch];

  const float* xg = x + (size_t)(batch * SEQ + s0) * HID;
  const unsigned short* bbase = Bct + (size_t)a * RANK * HID;

  f32x4 acc[4];
  #pragma unroll
  for (int nt = 0; nt < 4; ++nt) acc[nt] = (f32x4){0.f, 0.f, 0.f, 0.f};

  // ---------------- phase 1: Bx = x_tile @ B_a ----------------
  for (int kc = 0; kc < 4; ++kc) {
    if (kc) __syncthreads();             // prev chunk's xs reads complete
    // stage 16x1024 fp32 -> bf16 LDS in two batches of 4 rounds
    // (4-deep MLP, 16 VGPRs live -> no spill under the 64-VGPR cap).
    #pragma unroll
    for (int half = 0; half < 2; ++half) {
      f32x4 v[4];
      #pragma unroll
      for (int r = 0; r < 4; ++r) {
        int flat = (((half << 2) + r) << 11) + (t << 2);
        int row  = flat >> 10;
        int col  = flat & 1023;
        v[r] = __builtin_nontemporal_load(
            (const f32x4*)(xg + (size_t)row * HID + (kc << 10) + col));
      }
      #pragma unroll
      for (int r = 0; r < 4; ++r) {
        int flat = (((half << 2) + r) << 11) + (t << 2);
        int row  = flat >> 10;
        int col  = flat & 1023;
        int csw  = (col >> 3) ^ (row & 7);     // swizzle 16B chunks by row
        u32x2 pk;
        pk[0] = pack_bf16_2(v[r][0], v[r][1]);
        pk[1] = pack_bf16_2(v[r][2], v[r][3]);
        *(u32x2*)&xs[row * 1024 + (csw << 3) + (col & 7)] = pk;
      }
    }
    __syncthreads();
    // MFMA: wave w handles k_local in [w*128, w*128+128)
    #pragma unroll
    for (int j = 0; j < 4; ++j) {
      int kl  = (w << 7) + (j << 5) + (q << 3);
      int csw = (kl >> 3) ^ (m & 7);
      short8 af = *(const short8*)&xs[m * 1024 + (csw << 3)];
      int kglob = (kc << 10) + kl;
      #pragma unroll
      for (int nt = 0; nt < 4; ++nt) {
        short8 bf = *(const short8*)(bbase + (size_t)(nt * 16 + m) * HID + kglob);
        acc[nt] = __builtin_amdgcn_mfma_f32_16x16x32_bf16(af, bf, acc[nt], 0, 0, 0);
      }
    }
  }
  __syncthreads();   // all xs reads done before red overwrites the buffer

  // cross-wave reduce: C/D layout col = lane&15 (-> r), row = q*4+reg (-> s)
  #pragma unroll
  for (int nt = 0; nt < 4; ++nt)
    #pragma unroll
    for (int r = 0; r < 4; ++r)
      red[(w * 16 + q * 4 + r) * 65 + nt * 16 + m] = acc[nt][r];
  __syncthreads();

  if (t < 256) {
    int row = t >> 4;          // 0..15
    int rb  = (t & 15) << 2;   // 0,4,...,60
    float v0 = 0.f, v1 = 0.f, v2 = 0.f, v3 = 0.f;
    #pragma unroll
    for (int ww = 0; ww < 8; ++ww) {
      const float* rr = &red[(ww * 16 + row) * 65 + rb];
      v0 += rr[0]; v1 += rr[1]; v2 += rr[2]; v3 += rr[3];
    }
    const float sc = 1.0f / 64.0f;   // exact *1/64, commutes with bf16 rounding
    uint2 pk;
    pk.x = pack_bf16_2(v0 * sc, v1 * sc);
    pk.y = pack_bf16_2(v2 * sc, v3 * sc);
    *(uint2*)&bx[row * 72 + rb] = pk;
  }
  __syncthreads();   // bx ready; red fully consumed -> os may overwrite

  // ---------------- phase 2: out_tile = Bx @ A_a ----------------
  // Operand-swapped MFMA (A-frag = Act rows, B-frag = Bx): lane holds 4
  // contiguous o values -> stage to os (swizzled) -> streamed stores.
  short8 p0 = *(const short8*)&bx[m * 72 + (q << 3)];
  short8 p1 = *(const short8*)&bx[m * 72 + 32 + (q << 3)];
  const unsigned short* abase = Act + (size_t)a * OUTF * RANK;

  for (int oc = 0; oc < 8; ++oc) {
    int o0 = oc << 9;                       // this chunk: o in [o0, o0+512)
    #pragma unroll
    for (int nt = 0; nt < 4; ++nt) {
      const unsigned short* arow =
          abase + (size_t)(o0 + (w << 6) + nt * 16 + m) * RANK;
      short8 b0 = *(const short8*)(arow + (q << 3));
      short8 b1 = *(const short8*)(arow + 32 + (q << 3));
      f32x4 cc = (f32x4){0.f, 0.f, 0.f, 0.f};
      cc = __builtin_amdgcn_mfma_f32_16x16x32_bf16(b0, p0, cc, 0, 0, 0);
      cc = __builtin_amdgcn_mfma_f32_16x16x32_bf16(b1, p1, cc, 0, 0, 0);
      int ci  = (w << 4) + (nt << 2) + q;    // 16B chunk index within row
      *(f32x4*)&os[m * 512 + ((ci ^ (m & 7)) << 2)] = cc;
    }
    __syncthreads();
    // stream the 16x512 f32 tile: 4 rounds, 1KB contiguous per wave
    #pragma unroll
    for (int r = 0; r < 4; ++r) {
      int flat = (r << 11) + (t << 2);
      int row  = flat >> 9;
      int col  = flat & 511;
      int csw  = (col >> 2) ^ (row & 7);
      f32x4 vv = *(const f32x4*)&os[row * 512 + (csw << 2)];
      *(f32x4*)(out + (size_t)(batch * SEQ + s0 + row) * OUTF + o0 + col) = vv;
    }
    __syncthreads();   // os consumed before next chunk overwrites
  }
}

// ---------------------------------------------------------------------------
extern "C" void kernel_launch(void* const* d_in, const int* in_sizes, int n_in,
                              void* d_out, int out_size, void* d_ws, size_t ws_size,
                              hipStream_t stream) {
  const float* x   = (const float*)d_in[0];
  const int*   ids = (const int*)d_in[1];
  const float* A   = (const float*)d_in[2];
  const float* Bm  = (const float*)d_in[3];
  float*       out = (float*)d_out;

  // workspace layout (8 MB total):
  unsigned short* Bct = (unsigned short*)d_ws;                 // 8*64*4096*2 = 4 MB
  unsigned short* Act = Bct + (size_t)NA * RANK * HID;         // 8*4096*64*2 = 4 MB

  prep_kernel <<<1024, 256, 0, stream>>>(A, Bm, Bct, Act);
  fused_kernel<<<1024, 512, 0, stream>>>(x, ids, Bct, Act, out);
}

// Round 7
// 514.186 us; speedup vs baseline: 1.1006x; 1.0380x over previous
//
#include <hip/hip_runtime.h>

#define BATCH 4
#define SEQ   4096
#define HID   4096
#define OUTF  4096
#define NA    8
#define RANK  64

typedef __attribute__((ext_vector_type(8))) short  short8;
typedef __attribute__((ext_vector_type(4))) float  f32x4;
typedef __attribute__((ext_vector_type(2))) unsigned int u32x2;

// round-half-up fp32 -> bf16 (inputs are finite Gaussians; no NaN handling needed)
__device__ __forceinline__ unsigned short cvt_bf16(float f) {
  return (unsigned short)((__float_as_uint(f) + 0x8000u) >> 16);
}
__device__ __forceinline__ unsigned int pack_bf16_2(float lo, float hi) {
  unsigned int a = __float_as_uint(lo);
  unsigned int b = __float_as_uint(hi);
  return ((a + 0x8000u) >> 16) | ((b + 0x8000u) & 0xFFFF0000u);
}

// Raw workgroup barrier WITHOUT the __syncthreads vmcnt(0) drain: global
// loads/stores stay in flight across it. sched_barrier(0) on both sides
// pins ds ops to their side of the barrier (guide rule #18).
__device__ __forceinline__ void raw_barrier() {
  __builtin_amdgcn_sched_barrier(0);
  __builtin_amdgcn_s_barrier();
  __builtin_amdgcn_sched_barrier(0);
}
// Same, but first make this wave's LDS writes visible (producer side).
__device__ __forceinline__ void lds_fence_barrier() {
  __builtin_amdgcn_sched_barrier(0);
  asm volatile("s_waitcnt lgkmcnt(0)" ::: "memory");
  __builtin_amdgcn_s_barrier();
  __builtin_amdgcn_sched_barrier(0);
}

// ---------------------------------------------------------------------------
// Kernel 0: convert + transpose the small matrices so MFMA fragments are
// K-contiguous 16B loads.
//   Bct[a][r][h] = bf16(B[h][a][r])   (8 x 64 x 4096)
//   Act[a][o][r] = bf16(A[a][r][o])   (8 x 4096 x 64)
// ---------------------------------------------------------------------------
__global__ __launch_bounds__(256) void prep_kernel(
    const float* __restrict__ A, const float* __restrict__ Bm,
    unsigned short* __restrict__ Bct, unsigned short* __restrict__ Act) {
  __shared__ unsigned short lds[64 * 72];
  int bid = blockIdx.x;
  int t   = threadIdx.x;
  int lo  = t & 63;   // fast (coalesced) dim
  int hi4 = t >> 6;   // 0..3
  if (bid < 512) {
    int a  = bid >> 6;
    int h0 = (bid & 63) << 6;
    #pragma unroll
    for (int p = 0; p < 16; ++p) {          // read B[h][a][r], r = lo
      int hl = (p << 2) + hi4;
      float v = Bm[((size_t)(h0 + hl) * NA + a) * RANK + lo];
      lds[lo * 72 + hl] = cvt_bf16(v);      // lds[r][h]
    }
    __syncthreads();
    #pragma unroll
    for (int p = 0; p < 16; ++p) {          // write Bct[a][r][h], h = lo
      int rl = (p << 2) + hi4;
      Bct[((size_t)a * RANK + rl) * HID + h0 + lo] = lds[rl * 72 + lo];
    }
  } else {
    int b2 = bid - 512;
    int a  = b2 >> 6;
    int o0 = (b2 & 63) << 6;
    #pragma unroll
    for (int p = 0; p < 16; ++p) {          // read A[a][r][o], o = lo
      int rl = (p << 2) + hi4;
      float v = A[((size_t)a * RANK + rl) * OUTF + o0 + lo];
      lds[lo * 72 + rl] = cvt_bf16(v);      // lds[o][r]
    }
    __syncthreads();
    #pragma unroll
    for (int p = 0; p < 16; ++p) {          // write Act[a][o][r], r = lo
      int ol = (p << 2) + hi4;
      Act[((size_t)a * OUTF + o0 + ol) * RANK + lo] = lds[ol * 72 + lo];
    }
  }
}

// ---------------------------------------------------------------------------
// Fused kernel, v7: burst access (R5/R6) + pipelined memory across RAW
// barriers. R6 diagnosis: __syncthreads drains vmcnt(0) every chunk ->
// HBM idles during compute windows and vice versa -> BW clamped ~2.4 TB/s.
// v7: (a) phase-1 issues chunk kc+1's HBM loads into regs BEFORE the MFMA
// of chunk kc; only lgkmcnt-fenced raw barriers in the loops, so global
// loads/stores stay in flight across barriers. (b) phase-2 stores are
// never drained in-loop (fire-and-forget; LDS reuse only needs lgkm+bar).
// (c) __launch_bounds__(512,4): 128-VGPR budget kills R5/R6's scratch
// spill (R6: +32 MB WRITE / +14 MB FETCH of scratch traffic).
// Hazards: single xs buffer -- pack(kc+1) separated from all waves'
// MFMA(kc) reads by barrier_A; xs visibility by lds_fence_barrier.
// Single os buffer -- ds_write(oc+1) separated from all waves' ds_reads
// of oc by barrier_A (a wave reaching it has consumed its reads into vv).
// ---------------------------------------------------------------------------
__global__ __launch_bounds__(512, 4) void fused_kernel(
    const float* __restrict__ x, const int* __restrict__ ids,
    const unsigned short* __restrict__ Bct, const unsigned short* __restrict__ Act,
    float* __restrict__ out) {
  __shared__ float smem[8 * 16 * 65];          // 33.3 KB, aliased xs/red/os
  __shared__ unsigned short bx[16 * 72];       // Bx tile, bf16
  unsigned short* xs = (unsigned short*)smem;  // [16][1024] bf16, 16B-chunk swizzled
  float*          os = smem;                   // [16][512] f32, 16B-chunk swizzled
  float*          red = smem;                  // [8*16][65] f32 partials

  int bid   = blockIdx.x;
  int batch = bid & 3;          // XCD-pinned: XCD k -> batch k&3
  int s0    = (bid >> 2) << 4;
  int t     = threadIdx.x;
  int w     = t >> 6;           // 0..7
  int lane  = t & 63;
  int m     = lane & 15;
  int q     = lane >> 4;
  int a     = ids[batch];

  const float* xg = x + (size_t)(batch * SEQ + s0) * HID;
  const unsigned short* bbase = Bct + (size_t)a * RANK * HID;

  f32x4 acc[4];
  #pragma unroll
  for (int nt = 0; nt < 4; ++nt) acc[nt] = (f32x4){0.f, 0.f, 0.f, 0.f};

  // ---------------- phase 1: Bx = x_tile @ B_a ----------------
  f32x4 v[8];
  #pragma unroll
  for (int r = 0; r < 8; ++r) {              // prologue: chunk 0 loads
    int flat = (r << 11) + (t << 2);
    v[r] = __builtin_nontemporal_load(
        (const f32x4*)(xg + (size_t)(flat >> 10) * HID + (flat & 1023)));
  }

  #pragma unroll
  for (int kc = 0; kc < 4; ++kc) {
    if (kc) raw_barrier();                   // barrier_A: all MFMA(kc-1) xs reads done
    #pragma unroll
    for (int r = 0; r < 8; ++r) {            // pack v -> xs (counted vmcnt on v)
      int flat = (r << 11) + (t << 2);
      int row  = flat >> 10;
      int col  = flat & 1023;
      int csw  = (col >> 3) ^ (row & 7);     // swizzle 16B chunks by row
      u32x2 pk;
      pk[0] = pack_bf16_2(v[r][0], v[r][1]);
      pk[1] = pack_bf16_2(v[r][2], v[r][3]);
      *(u32x2*)&xs[row * 1024 + (csw << 3) + (col & 7)] = pk;
    }
    if (kc < 3) {
      #pragma unroll
      for (int r = 0; r < 8; ++r) {          // next chunk's loads: fly across MFMA
        int flat = (r << 11) + (t << 2);
        v[r] = __builtin_nontemporal_load(
            (const f32x4*)(xg + (size_t)(flat >> 10) * HID + ((kc + 1) << 10) + (flat & 1023)));
      }
    }
    lds_fence_barrier();                     // barrier_B: xs visible, no vmcnt drain
    #pragma unroll
    for (int j = 0; j < 4; ++j) {            // wave w: k_local in [w*128, w*128+128)
      int kl  = (w << 7) + (j << 5) + (q << 3);
      int csw = (kl >> 3) ^ (m & 7);
      short8 af = *(const short8*)&xs[m * 1024 + (csw << 3)];
      int kglob = (kc << 10) + kl;
      #pragma unroll
      for (int nt = 0; nt < 4; ++nt) {
        short8 bf = *(const short8*)(bbase + (size_t)(nt * 16 + m) * HID + kglob);
        acc[nt] = __builtin_amdgcn_mfma_f32_16x16x32_bf16(af, bf, acc[nt], 0, 0, 0);
      }
    }
  }
  __syncthreads();   // full drain once: xs reads done before red overwrites

  // cross-wave reduce: C/D layout col = lane&15 (-> r), row = q*4+reg (-> s)
  #pragma unroll
  for (int nt = 0; nt < 4; ++nt)
    #pragma unroll
    for (int r = 0; r < 4; ++r)
      red[(w * 16 + q * 4 + r) * 65 + nt * 16 + m] = acc[nt][r];
  __syncthreads();

  if (t < 256) {
    int row = t >> 4;          // 0..15
    int rb  = (t & 15) << 2;   // 0,4,...,60
    float v0 = 0.f, v1 = 0.f, v2 = 0.f, v3 = 0.f;
    #pragma unroll
    for (int ww = 0; ww < 8; ++ww) {
      const float* rr = &red[(ww * 16 + row) * 65 + rb];
      v0 += rr[0]; v1 += rr[1]; v2 += rr[2]; v3 += rr[3];
    }
    const float sc = 1.0f / 64.0f;   // exact *1/64, commutes with bf16 rounding
    uint2 pk;
    pk.x = pack_bf16_2(v0 * sc, v1 * sc);
    pk.y = pack_bf16_2(v2 * sc, v3 * sc);
    *(uint2*)&bx[row * 72 + rb] = pk;
  }
  __syncthreads();   // bx ready; red fully consumed -> os may overwrite

  // ---------------- phase 2: out_tile = Bx @ A_a ----------------
  // Operand-swapped MFMA (A-frag = Act rows, B-frag = Bx): lane holds 4
  // contiguous o values -> stage to os (swizzled) -> 1KB/wave burst stores.
  short8 p0 = *(const short8*)&bx[m * 72 + (q << 3)];
  short8 p1 = *(const short8*)&bx[m * 72 + 32 + (q << 3)];
  const unsigned short* abase = Act + (size_t)a * OUTF * RANK;
  float* outp = out + (size_t)(batch * SEQ + s0) * OUTF;

  for (int oc = 0; oc < 8; ++oc) {
    int o0 = oc << 9;                       // this chunk: o in [o0, o0+512)
    f32x4 cc[4];
    #pragma unroll
    for (int nt = 0; nt < 4; ++nt) {        // Act loads are L2-resident
      const unsigned short* arow =
          abase + (size_t)(o0 + (w << 6) + nt * 16 + m) * RANK;
      short8 b0 = *(const short8*)(arow + (q << 3));
      short8 b1 = *(const short8*)(arow + 32 + (q << 3));
      cc[nt] = (f32x4){0.f, 0.f, 0.f, 0.f};
      cc[nt] = __builtin_amdgcn_mfma_f32_16x16x32_bf16(b0, p0, cc[nt], 0, 0, 0);
      cc[nt] = __builtin_amdgcn_mfma_f32_16x16x32_bf16(b1, p1, cc[nt], 0, 0, 0);
    }
    if (oc) raw_barrier();                  // barrier_A: all ds_reads of prev os done
    #pragma unroll
    for (int nt = 0; nt < 4; ++nt) {
      int ci = (w << 4) + (nt << 2) + q;    // 16B chunk index within row
      *(f32x4*)&os[m * 512 + ((ci ^ (m & 7)) << 2)] = cc[nt];
    }
    lds_fence_barrier();                    // barrier_B: os visible, stores NOT drained
    #pragma unroll
    for (int r = 0; r < 4; ++r) {           // 1KB contiguous per wave per round
      int flat = (r << 11) + (t << 2);
      int row  = flat >> 9;
      int col  = flat & 511;
      int csw  = (col >> 2) ^ (row & 7);
      f32x4 vv = *(const f32x4*)&os[row * 512 + (csw << 2)];
      *(f32x4*)(outp + (size_t)row * OUTF + o0 + col) = vv;   // fire-and-forget
    }
  }
}

// ---------------------------------------------------------------------------
extern "C" void kernel_launch(void* const* d_in, const int* in_sizes, int n_in,
                              void* d_out, int out_size, void* d_ws, size_t ws_size,
                              hipStream_t stream) {
  const float* x   = (const float*)d_in[0];
  const int*   ids = (const int*)d_in[1];
  const float* A   = (const float*)d_in[2];
  const float* Bm  = (const float*)d_in[3];
  float*       out = (float*)d_out;

  // workspace layout (8 MB total):
  unsigned short* Bct = (unsigned short*)d_ws;                 // 8*64*4096*2 = 4 MB
  unsigned short* Act = Bct + (size_t)NA * RANK * HID;         // 8*4096*64*2 = 4 MB

  prep_kernel <<<1024, 256, 0, stream>>>(A, Bm, Bct, Act);
  fused_kernel<<<1024, 512, 0, stream>>>(x, ids, Bct, Act, out);
}